// Round 4
// baseline (229.314 us; speedup 1.0000x reference)
//
#include <hip/hip_runtime.h>
#include <hip/hip_cooperative_groups.h>
#include <math.h>

namespace cg = cooperative_groups;

#define B_SZ 256
#define N_TOK 5000
#define DM 128
#define DC 384
#define DK 128
#define NBLK 4      // blocks per batch row (1024 blocks = 4/CU, co-resident)
#define CHUNK 1250  // token rows per block

// ---------------------------------------------------------------------------
// Kernel A: per-b projection, f64 accumulation (tiny).
//   Q[b]  = Wq @ ctxt[b] + bq   (f64 acc, float4 loads, 4-way ILP)
//   v[b]  = Wk^T @ Q[b]         (f64 acc)
//   c[b]  = Q[b] . bk           (f64 acc)
// ---------------------------------------------------------------------------
__global__ __launch_bounds__(128) void proj_kernel(
    const float* __restrict__ ctxt, const float* __restrict__ Wq,
    const float* __restrict__ bq, const float* __restrict__ Wk,
    const float* __restrict__ bk, float* __restrict__ v,
    float* __restrict__ c) {
  const int b = blockIdx.x;
  const int t = threadIdx.x;  // 0..127
  __shared__ float4 s_ctxt4[DC / 4];  // 96
  __shared__ double s_Q[DK];

  const float4* ctxt4 = reinterpret_cast<const float4*>(ctxt + (size_t)b * DC);
  for (int i = t; i < DC / 4; i += 128) s_ctxt4[i] = ctxt4[i];
  __syncthreads();

  const float4* wr = reinterpret_cast<const float4*>(Wq + (size_t)t * DC);
  double a0 = (double)bq[t], a1 = 0.0, a2 = 0.0, a3 = 0.0;
#pragma unroll 8
  for (int i = 0; i < DC / 4; ++i) {
    const float4 w = wr[i];
    const float4 cc4 = s_ctxt4[i];
    a0 += (double)w.x * (double)cc4.x;
    a1 += (double)w.y * (double)cc4.y;
    a2 += (double)w.z * (double)cc4.z;
    a3 += (double)w.w * (double)cc4.w;
  }
  s_Q[t] = (a0 + a1) + (a2 + a3);
  __syncthreads();

  // v[m=t] = sum_k Q[k] * Wk[k, t]   (coalesced over t)
  double v0 = 0.0, v1 = 0.0, v2 = 0.0, v3 = 0.0;
#pragma unroll 4
  for (int k = 0; k < DK; k += 4) {
    v0 += s_Q[k] * (double)Wk[(size_t)k * DM + t];
    v1 += s_Q[k + 1] * (double)Wk[(size_t)(k + 1) * DM + t];
    v2 += s_Q[k + 2] * (double)Wk[(size_t)(k + 2) * DM + t];
    v3 += s_Q[k + 3] * (double)Wk[(size_t)(k + 3) * DM + t];
  }
  v[b * DM + t] = (float)((v0 + v1) + (v2 + v3));

  if (t == 0) {
    double cb = 0.0;
    for (int k = 0; k < DK; ++k) cb += s_Q[k] * (double)bk[k];
    c[b] = (float)cb;
  }
}

// ---------------------------------------------------------------------------
// Fused cooperative kernel: stream + dot -> LDS, tanh/exp/mask -> LDS,
// per-block partial, grid.sync, normalize, single global write of out.
// 16 lanes per 512B row; per wave-iter the 4 quarters cover 4 contiguous
// rows (2KB); per block-iter 16 rows. 78 iters * 16 = 1248, +2 tail rows.
// ---------------------------------------------------------------------------
__global__ __launch_bounds__(256, 4) void fused_kernel(
    const float* __restrict__ emb, const float* __restrict__ mask,
    const float* __restrict__ v, const float* __restrict__ c,
    float* __restrict__ out, float* __restrict__ partial) {
  const int bid = blockIdx.x;
  const int b = bid >> 2;       // batch row
  const int x = bid & 3;        // chunk within row
  const int nstart = x * CHUNK;
  const int tid = threadIdx.x;
  const int wave = tid >> 6;
  const int lane = tid & 63;
  const int q = lane >> 4;   // quarter: which of 4 rows in this wave-iter
  const int cc = lane & 15;  // 16 lanes cover one 512 B row

  __shared__ float s_d[CHUNK];
  __shared__ float s_red[4];

  const float4 vv0 = *reinterpret_cast<const float4*>(v + b * DM + 4 * cc);
  const float4 vv1 =
      *reinterpret_cast<const float4*>(v + b * DM + 64 + 4 * cc);

  const float* embb = emb + (size_t)b * N_TOK * DM;
  const float* p0 = embb + (size_t)(nstart + wave * 4 + q) * DM + 4 * cc;

  // main loop: 78 iterations x 16 rows = 1248 rows, no guard
#pragma unroll 3
  for (int it = 0; it < 78; ++it) {
    const float* p = p0 + (size_t)it * 16 * DM;
    const float4 e0 = *reinterpret_cast<const float4*>(p);
    const float4 e1 = *reinterpret_cast<const float4*>(p + 64);
    float d = e0.x * vv0.x + e0.y * vv0.y + e0.z * vv0.z + e0.w * vv0.w +
              e1.x * vv1.x + e1.y * vv1.y + e1.z * vv1.z + e1.w * vv1.w;
    d += __shfl_xor(d, 1);
    d += __shfl_xor(d, 2);
    d += __shfl_xor(d, 4);
    d += __shfl_xor(d, 8);
    if (cc == 0) s_d[it * 16 + wave * 4 + q] = d;
  }
  // tail rows 1248,1249: wave 0, quarters 0..1
  if (wave == 0 && q < 2) {
    const float* p = embb + (size_t)(nstart + 1248 + q) * DM + 4 * cc;
    const float4 e0 = *reinterpret_cast<const float4*>(p);
    const float4 e1 = *reinterpret_cast<const float4*>(p + 64);
    float d = e0.x * vv0.x + e0.y * vv0.y + e0.z * vv0.z + e0.w * vv0.w +
              e1.x * vv1.x + e1.y * vv1.y + e1.z * vv1.z + e1.w * vv1.w;
    d += __shfl_xor(d, 1);
    d += __shfl_xor(d, 2);
    d += __shfl_xor(d, 4);
    d += __shfl_xor(d, 8);
    if (cc == 0) s_d[1248 + q] = d;
  }
  __syncthreads();

  // phase 2: full-width transcendentals into LDS + block partial sum
  const float cb = c[b];
  const float inv_sqrt = 0.08838834764831845f;  // 1/sqrt(128)
  const float* maskb = mask + (size_t)b * N_TOK + nstart;
  float lsum = 0.0f;
  for (int i = tid; i < CHUNK; i += 256) {
    const float u = (s_d[i] + cb) * inv_sqrt;
    const float t = 10.0f * tanhf(u) + maskb[i];
    const float e = expf(t);
    s_d[i] = e;
    lsum += e;
  }
  // deterministic wave butterfly + fixed-order cross-wave sum
  lsum += __shfl_xor(lsum, 1);
  lsum += __shfl_xor(lsum, 2);
  lsum += __shfl_xor(lsum, 4);
  lsum += __shfl_xor(lsum, 8);
  lsum += __shfl_xor(lsum, 16);
  lsum += __shfl_xor(lsum, 32);
  if (lane == 0) s_red[wave] = lsum;
  __syncthreads();
  if (tid == 0) {
    partial[bid] = (s_red[0] + s_red[1]) + (s_red[2] + s_red[3]);
    __threadfence();  // make partial device-visible before the grid barrier
  }

  cg::this_grid().sync();

  // phase 3: fixed-order sum of the 4 partials, single write of out
  const float s = (partial[b * NBLK + 0] + partial[b * NBLK + 1]) +
                  (partial[b * NBLK + 2] + partial[b * NBLK + 3]);
  const float inv = 1.0f / s;
  float* outb = out + (size_t)b * N_TOK + nstart;
  for (int i = tid; i < CHUNK; i += 256) outb[i] = s_d[i] * inv;
}

extern "C" void kernel_launch(void* const* d_in, const int* in_sizes, int n_in,
                              void* d_out, int out_size, void* d_ws,
                              size_t ws_size, hipStream_t stream) {
  const float* ctxt = (const float*)d_in[0];  // [B,1,384]
  const float* emb  = (const float*)d_in[1];  // [B,5000,128]
  const float* mask = (const float*)d_in[2];  // [B,1,5000]
  const float* Wq   = (const float*)d_in[3];  // [128,384]
  const float* bq   = (const float*)d_in[4];  // [128]
  const float* Wk   = (const float*)d_in[5];  // [128,128]
  const float* bk   = (const float*)d_in[6];  // [128]
  float* out = (float*)d_out;                 // [B,1,5000]

  float* v = (float*)d_ws;        // [B,128]
  float* c = v + B_SZ * DM;       // [B]
  float* partial = c + B_SZ;      // [B*NBLK]

  proj_kernel<<<B_SZ, 128, 0, stream>>>(ctxt, Wq, bq, Wk, bk, v, c);

  void* args[] = {(void*)&emb, (void*)&mask, (void*)&v, (void*)&c,
                  (void*)&out, (void*)&partial};
  hipLaunchCooperativeKernel((const void*)fused_kernel, dim3(B_SZ * NBLK),
                             dim3(256), args, 0, stream);
}

// Round 5
// 144.429 us; speedup vs baseline: 1.5877x; 1.5877x over previous
//
#include <hip/hip_runtime.h>
#include <math.h>

#define B_SZ 256
#define N_TOK 5000
#define DM 128
#define DC 384
#define DK 128
#define NBLK 8     // score blocks per batch row
#define CHUNK 625  // token rows per score block

// ---------------------------------------------------------------------------
// Kernel A: per-b projection, f64 accumulation (tiny), latency-optimized.
//   waves 0-1: Q = Wq @ ctxt[b] + bq  (float4 loads, unroll 16, f64 acc)
//   waves 2-3: stage Wk (64 KB) into LDS concurrently
//   phase v:   v = Wk^T @ Q from LDS  (f64 acc)
//   phase c:   c = Q . bk, 64-lane parallel + deterministic f64 butterfly
// ---------------------------------------------------------------------------
__global__ __launch_bounds__(256) void proj_kernel(
    const float* __restrict__ ctxt, const float* __restrict__ Wq,
    const float* __restrict__ bq, const float* __restrict__ Wk,
    const float* __restrict__ bk, float* __restrict__ v,
    float* __restrict__ c) {
  const int b = blockIdx.x;
  const int tid = threadIdx.x;
  __shared__ float s_ctxt[DC];
  __shared__ double s_Q[DK];
  __shared__ float s_Wk[DK * DM];  // 64 KB

  if (tid < DC / 4) {
    reinterpret_cast<float4*>(s_ctxt)[tid] =
        reinterpret_cast<const float4*>(ctxt + (size_t)b * DC)[tid];
  }
  __syncthreads();

  if (tid < 128) {
    // waves 0,1: Q[tid] in f64, 4-way ILP, deep unroll for load overlap
    const float4* wr = reinterpret_cast<const float4*>(Wq + (size_t)tid * DC);
    const float4* c4 = reinterpret_cast<const float4*>(s_ctxt);
    double a0 = (double)bq[tid], a1 = 0.0, a2 = 0.0, a3 = 0.0;
#pragma unroll 16
    for (int i = 0; i < DC / 4; ++i) {
      const float4 w = wr[i];
      const float4 cc = c4[i];
      a0 += (double)w.x * (double)cc.x;
      a1 += (double)w.y * (double)cc.y;
      a2 += (double)w.z * (double)cc.z;
      a3 += (double)w.w * (double)cc.w;
    }
    s_Q[tid] = (a0 + a1) + (a2 + a3);
  } else {
    // waves 2,3: stage Wk into LDS (coalesced float4, 8 in flight)
    const float4* g = reinterpret_cast<const float4*>(Wk);
    float4* s4 = reinterpret_cast<float4*>(s_Wk);
    const int t = tid - 128;
#pragma unroll 8
    for (int i = 0; i < (DK * DM / 4) / 128; ++i)
      s4[i * 128 + t] = g[i * 128 + t];
  }
  __syncthreads();

  if (tid < 128) {
    // v[m=tid] = sum_k Q[k] * Wk[k, m], all operands in LDS
    double v0 = 0.0, v1 = 0.0, v2 = 0.0, v3 = 0.0;
#pragma unroll 8
    for (int k = 0; k < DK; k += 4) {
      v0 += s_Q[k] * (double)s_Wk[k * DM + tid];
      v1 += s_Q[k + 1] * (double)s_Wk[(k + 1) * DM + tid];
      v2 += s_Q[k + 2] * (double)s_Wk[(k + 2) * DM + tid];
      v3 += s_Q[k + 3] * (double)s_Wk[(k + 3) * DM + tid];
    }
    v[b * DM + tid] = (float)((v0 + v1) + (v2 + v3));
  }
  if (tid < 64) {
    // c[b] = Q . bk, 64-lane parallel, deterministic butterfly (f64)
    double cp = s_Q[tid] * (double)bk[tid] + s_Q[tid + 64] * (double)bk[tid + 64];
    cp += __shfl_xor(cp, 1);
    cp += __shfl_xor(cp, 2);
    cp += __shfl_xor(cp, 4);
    cp += __shfl_xor(cp, 8);
    cp += __shfl_xor(cp, 16);
    cp += __shfl_xor(cp, 32);
    if (tid == 0) c[b] = (float)cp;
  }
}

// ---------------------------------------------------------------------------
// Kernel B: two-phase. Phase 1 streams emb, computes raw dots into LDS
// (no transcendentals in the hot loop). Phase 2 (full-width lanes) applies
// tanh-clip + mask + exp, writes e, reduces the block partial sum.
// ---------------------------------------------------------------------------
__global__ __launch_bounds__(256) void score_kernel(
    const float* __restrict__ emb, const float* __restrict__ mask,
    const float* __restrict__ v, const float* __restrict__ c,
    float* __restrict__ out, float* __restrict__ partial) {
  const int b = blockIdx.y;
  const int nstart = blockIdx.x * CHUNK;
  const int tid = threadIdx.x;
  const int wave = tid >> 6;
  const int lane = tid & 63;
  const int q = lane >> 4;   // quarter-wave: which of 4 rows
  const int cc = lane & 15;  // 16 lanes cover one 512 B row

  __shared__ float s_d[CHUNK];
  __shared__ float s_red[256];

  const float4 vv0 = *reinterpret_cast<const float4*>(v + b * DM + 4 * cc);
  const float4 vv1 =
      *reinterpret_cast<const float4*>(v + b * DM + 64 + 4 * cc);

  const float* embb = emb + (size_t)b * N_TOK * DM;
  const float* p0 = embb + (size_t)(nstart + wave * 4 + q) * DM + 4 * cc;

  // main loop: 39 iterations x 16 rows/block-iter = 624 rows, no guard
#pragma unroll 2
  for (int it = 0; it < 39; ++it) {
    const float* p = p0 + (size_t)it * 16 * DM;
    const float4 e0 = *reinterpret_cast<const float4*>(p);
    const float4 e1 = *reinterpret_cast<const float4*>(p + 64);
    float d = e0.x * vv0.x + e0.y * vv0.y + e0.z * vv0.z + e0.w * vv0.w +
              e1.x * vv1.x + e1.y * vv1.y + e1.z * vv1.z + e1.w * vv1.w;
    d += __shfl_xor(d, 1);
    d += __shfl_xor(d, 2);
    d += __shfl_xor(d, 4);
    d += __shfl_xor(d, 8);
    if (cc == 0) s_d[it * 16 + wave * 4 + q] = d;
  }
  // epilogue: row 624 (each quarter of wave 0 redundantly computes it)
  if (wave == 0) {
    const float* p = embb + (size_t)(nstart + 624) * DM + 4 * cc;
    const float4 e0 = *reinterpret_cast<const float4*>(p);
    const float4 e1 = *reinterpret_cast<const float4*>(p + 64);
    float d = e0.x * vv0.x + e0.y * vv0.y + e0.z * vv0.z + e0.w * vv0.w +
              e1.x * vv1.x + e1.y * vv1.y + e1.z * vv1.z + e1.w * vv1.w;
    d += __shfl_xor(d, 1);
    d += __shfl_xor(d, 2);
    d += __shfl_xor(d, 4);
    d += __shfl_xor(d, 8);
    if (lane == 0) s_d[624] = d;
  }
  __syncthreads();

  // phase 2: full-width transcendentals + partial sum
  const float cb = c[b];
  const float inv_sqrt = 0.08838834764831845f;  // 1/sqrt(128)
  const float* maskb = mask + (size_t)b * N_TOK + nstart;
  float* outb = out + (size_t)b * N_TOK + nstart;
  float lsum = 0.0f;
  for (int i = tid; i < CHUNK; i += 256) {
    const float u = (s_d[i] + cb) * inv_sqrt;
    const float t = 10.0f * tanhf(u) + maskb[i];
    const float e = expf(t);
    outb[i] = e;
    lsum += e;
  }
  s_red[tid] = lsum;
  __syncthreads();
  for (int off = 128; off > 0; off >>= 1) {
    if (tid < off) s_red[tid] += s_red[tid + off];
    __syncthreads();
  }
  if (tid == 0) partial[b * NBLK + blockIdx.x] = s_red[0];
}

// ---------------------------------------------------------------------------
// Kernel C: normalize. Sums the 8 per-block partials in fixed order
// (deterministic), scales the L3-hot e values.
// ---------------------------------------------------------------------------
__global__ __launch_bounds__(256) void norm_kernel(
    float* __restrict__ out, const float* __restrict__ partial) {
  const int b = blockIdx.y;
  const int nstart = blockIdx.x * CHUNK;
  float s = 0.0f;
#pragma unroll
  for (int i = 0; i < NBLK; ++i) s += partial[b * NBLK + i];
  const float inv = 1.0f / s;
  float* outb = out + (size_t)b * N_TOK + nstart;
  for (int i = threadIdx.x; i < CHUNK; i += 256) outb[i] *= inv;
}

extern "C" void kernel_launch(void* const* d_in, const int* in_sizes, int n_in,
                              void* d_out, int out_size, void* d_ws,
                              size_t ws_size, hipStream_t stream) {
  const float* ctxt = (const float*)d_in[0];  // [B,1,384]
  const float* emb  = (const float*)d_in[1];  // [B,5000,128]
  const float* mask = (const float*)d_in[2];  // [B,1,5000]
  const float* Wq   = (const float*)d_in[3];  // [128,384]
  const float* bq   = (const float*)d_in[4];  // [128]
  const float* Wk   = (const float*)d_in[5];  // [128,128]
  const float* bk   = (const float*)d_in[6];  // [128]
  float* out = (float*)d_out;                 // [B,1,5000]

  float* v = (float*)d_ws;                 // [B,128]
  float* c = v + B_SZ * DM;                // [B]
  float* partial = c + B_SZ;               // [B, NBLK]

  proj_kernel<<<B_SZ, 256, 0, stream>>>(ctxt, Wq, bq, Wk, bk, v, c);
  score_kernel<<<dim3(NBLK, B_SZ), 256, 0, stream>>>(emb, mask, v, c, out,
                                                     partial);
  norm_kernel<<<dim3(NBLK, B_SZ), 256, 0, stream>>>(out, partial);
}